// Round 1
// baseline (441.991 us; speedup 1.0000x reference)
//
#include <hip/hip_runtime.h>
#include <stdint.h>

#define N_NODES 100000
#define N_EDGES 1600000

typedef __attribute__((ext_vector_type(8))) short short8;
typedef __attribute__((ext_vector_type(4))) float float4v;

__device__ __forceinline__ unsigned short f32_to_bf16(float f) {
  uint32_t u = __float_as_uint(f);
  u += 0x7fffu + ((u >> 16) & 1u);   // RNE
  return (unsigned short)(u >> 16);
}
__device__ __forceinline__ float bf16_to_f32(unsigned short h) {
  return __uint_as_float(((uint32_t)h) << 16);
}

// ---------------------------------------------------------------------------
// K0: per-node x_root = x @ root_weight, r_dot = x_root . att_w[:32];
//     also zero accum/denom (ws is poisoned 0xAA every call).
// 8 nodes per 256-thread block, lane = f_out.
// ---------------------------------------------------------------------------
__global__ __launch_bounds__(256) void k0_node_pre(
    const float* __restrict__ x, const float* __restrict__ root_w,
    const float* __restrict__ att_w,
    float* __restrict__ x_root, float* __restrict__ r_dot,
    float* __restrict__ accum, float* __restrict__ denom) {
  __shared__ float rw[32 * 32];
  __shared__ float xs[8 * 32];
  __shared__ float a1[32];
  int tid = threadIdx.x;
  int n0 = blockIdx.x * 8;
  for (int i = tid; i < 1024; i += 256) rw[i] = root_w[i];
  if (tid < 32) a1[tid] = att_w[tid];
  int nl = tid >> 5, f = tid & 31;
  int n = n0 + nl;
  xs[tid] = (n < N_NODES) ? x[n * 32 + f] : 0.f;
  __syncthreads();
  float acc = 0.f;
#pragma unroll
  for (int kk = 0; kk < 32; kk++) acc += xs[nl * 32 + kk] * rw[kk * 32 + f];
  if (n < N_NODES) {
    x_root[n * 32 + f] = acc;
    accum[n * 32 + f] = 0.f;
    if (f == 0) denom[n] = 0.f;
  }
  float v = acc * a1[f];
#pragma unroll
  for (int m = 16; m >= 1; m >>= 1) v += __shfl_xor(v, m, 32);
  if (f == 0 && n < N_NODES) r_dot[n] = v;
}

// ---------------------------------------------------------------------------
// K1: xw[n][k][fo] = (x @ weight[k])[n][fo], bf16 out, via MFMA 16x16x32 bf16.
// Block = 256 thr = 4 waves, 64 nodes. LDS holds W (all 25 mats) pre-swizzled
// into B-fragment order + the 64-node A tile in A-fragment order.
// A-frag: lane holds A[m=lane&15][k=quad*8+j]; B-frag: B[k=quad*8+j][n=lane&15];
// D: col=lane&15, row=quad*4+reg.
// ---------------------------------------------------------------------------
__global__ __launch_bounds__(256) void k1_xw(
    const float* __restrict__ x, const float* __restrict__ weight,
    unsigned short* __restrict__ xw) {
  __shared__ unsigned short wl[25600];  // 50 col-tiles x 4 q x 16 c x 8 j
  __shared__ unsigned short al[2048];   // 4 g x 4 q x 16 m x 8 j
  int tid = threadIdx.x;
  int n0 = blockIdx.x * 64;

  for (int e = tid; e < 25600; e += 256) {   // weight[km][kk][fo], fp32->bf16
    int km = e >> 10;
    int rem = e & 1023;
    int kk = rem >> 5;
    int fo = rem & 31;
    int t = km * 2 + (fo >> 4);
    int c = fo & 15;
    int q = kk >> 3, j = kk & 7;
    wl[((t * 4 + q) * 16 + c) * 8 + j] = f32_to_bf16(weight[e]);
  }
  for (int e = tid; e < 2048; e += 256) {    // x tile
    int nl = e >> 5, kk = e & 31;
    int n = n0 + nl;
    float v = (n < N_NODES) ? x[n * 32 + kk] : 0.f;
    int g = nl >> 4, m = nl & 15;
    int q = kk >> 3, j = kk & 7;
    al[((g * 4 + q) * 16 + m) * 8 + j] = f32_to_bf16(v);
  }
  __syncthreads();

  int wave = tid >> 6, lane = tid & 63;
  int quad = lane >> 4, c16 = lane & 15;
  short8 afrag = *reinterpret_cast<short8*>(&al[((wave * 4 + quad) * 16 + c16) * 8]);
  for (int t = 0; t < 50; t++) {
    short8 bfrag = *reinterpret_cast<short8*>(&wl[((t * 4 + quad) * 16 + c16) * 8]);
    float4v acc = {0.f, 0.f, 0.f, 0.f};
    acc = __builtin_amdgcn_mfma_f32_16x16x32_bf16(afrag, bfrag, acc, 0, 0, 0);
    int cg = t * 16 + c16;
#pragma unroll
    for (int r = 0; r < 4; r++) {
      int node = n0 + wave * 16 + quad * 4 + r;
      if (node < N_NODES) xw[(size_t)node * 800 + cg] = f32_to_bf16(acc[r]);
    }
  }
}

// ---------------------------------------------------------------------------
// K2: one 32-lane group per edge (8 edges / 256-thr block), lane = f_out.
// Gather 4 spline rows (64B each, coalesced across lanes), msg = sum b_s*row_s,
// alpha = leakyrelu(r_dot[row] + msg.a2) (no segment-max: shift-invariant,
// |alpha| <~ 1 here), atomic accumulate msg*exp and exp per target node.
// ---------------------------------------------------------------------------
__global__ __launch_bounds__(256) void k2_edge(
    const int* __restrict__ ei, const float* __restrict__ pseudo,
    const unsigned short* __restrict__ xw,
    const float* __restrict__ r_dot, const float* __restrict__ att_w,
    float* __restrict__ accum, float* __restrict__ denom) {
  int tid = threadIdx.x;
  int eg = blockIdx.x * 8 + (tid >> 5);
  int f = tid & 31;
  if (eg >= N_EDGES) return;
  int row = ei[eg];
  int col = ei[N_EDGES + eg];
  float p0 = pseudo[eg * 2 + 0] * 4.f;
  float p1 = pseudo[eg * 2 + 1] * 4.f;
  float fl0 = floorf(p0), fl1 = floorf(p1);
  float fr0 = p0 - fl0, fr1 = p1 - fl1;
  int i0 = (int)fl0, i1 = (int)fl1;

  const unsigned short* base = xw + (size_t)col * 800 + f;
  float msg = 0.f;
#pragma unroll
  for (int s = 0; s < 4; s++) {
    int o0 = s & 1, o1 = (s >> 1) & 1;
    int w = min(i0 + o0, 4) + 5 * min(i1 + o1, 4);
    float b = (o0 ? fr0 : 1.f - fr0) * (o1 ? fr1 : 1.f - fr1);
    msg += b * bf16_to_f32(base[w * 32]);
  }
  float a2 = att_w[32 + f];
  float v = msg * a2;
#pragma unroll
  for (int m = 16; m >= 1; m >>= 1) v += __shfl_xor(v, m, 32);
  float alpha = r_dot[row] + v;
  alpha = alpha > 0.f ? alpha : 0.2f * alpha;
  float ex = __expf(alpha);
  unsafeAtomicAdd(&accum[row * 32 + f], msg * ex);
  if (f == 0) unsafeAtomicAdd(&denom[row], ex);
}

// ---------------------------------------------------------------------------
// K3: out = accum/(denom+1e-16) + x_root + bias
// ---------------------------------------------------------------------------
__global__ __launch_bounds__(256) void k3_out(
    const float* __restrict__ accum, const float* __restrict__ denom,
    const float* __restrict__ x_root, const float* __restrict__ bias,
    float* __restrict__ out) {
  int i = blockIdx.x * 256 + threadIdx.x;
  if (i >= N_NODES * 32) return;
  int n = i >> 5, f = i & 31;
  out[i] = accum[i] / (denom[n] + 1e-16f) + x_root[i] + bias[f];
}

extern "C" void kernel_launch(void* const* d_in, const int* in_sizes, int n_in,
                              void* d_out, int out_size, void* d_ws, size_t ws_size,
                              hipStream_t stream) {
  const float* x      = (const float*)d_in[0];
  const int*   ei     = (const int*)d_in[1];
  const float* pseudo = (const float*)d_in[2];
  const float* weight = (const float*)d_in[3];
  const float* root_w = (const float*)d_in[4];
  const float* att_w  = (const float*)d_in[5];
  const float* bias   = (const float*)d_in[6];
  float* out = (float*)d_out;

  char* ws = (char*)d_ws;
  unsigned short* xw = (unsigned short*)ws;          // 100000*800*2 = 160,000,000 B
  float* x_root = (float*)(ws + 160000000);          // 12,800,000 B
  float* r_dot  = (float*)(ws + 172800000);          //    400,000 B
  float* accum  = (float*)(ws + 173200000);          // 12,800,000 B
  float* denom  = (float*)(ws + 186000000);          //    400,000 B

  hipLaunchKernelGGL(k0_node_pre, dim3(12500), dim3(256), 0, stream,
                     x, root_w, att_w, x_root, r_dot, accum, denom);
  hipLaunchKernelGGL(k1_xw, dim3(1563), dim3(256), 0, stream, x, weight, xw);
  hipLaunchKernelGGL(k2_edge, dim3(200000), dim3(256), 0, stream,
                     ei, pseudo, xw, r_dot, att_w, accum, denom);
  hipLaunchKernelGGL(k3_out, dim3(12500), dim3(256), 0, stream,
                     accum, denom, x_root, bias, out);
}